// Round 22
// baseline (27.857 us; speedup 1.0000x reference)
//
#include <hip/hip_runtime.h>

// Indexed segmented linear, bucketed-by-element grouped GEMM with bf16 MFMA.
//   segments (mi, mo, d): (96,96,1), (64,64,3), (32,32,5)
//   y[b, o*d+m] = sum_i x[b, i*d+m] * W[idx[b], i*mo+o]
//
// SINGLE-KERNEL pipeline (R20 + front-end overlap; R21 race FIXED):
//   gemm (3*64*8 x 512): one block = (segment, element e, tile). Each block:
//     0. W phase-A f32 loads issue FIRST (register clause) — latency hides
//        under the scan.
//     1. int4-vectorized rank-scan of widx (8 loads/thread; row =
//        4*(k*512+t)+b) -> rid_s + cnt. cnt stays in REGISTERS (R21 stashed
//        it to LDS without a barrier -> divergent early-exit -> deadlock).
//        Uniform early-exit if lo >= cnt.
//     2. W phase A writes (bf16 -> lw[i][o]); ONE barrier publishes both lw
//        and rid_s; x gather clause issues, overlapping W phase B transpose
//        (lw -> lds_w[o][i] packed us8).
//     3. packed de-interleave x -> lds_x; MFMA (4 row-tiles x D x NT over
//        8 waves); 2-pass transpose epilogue; row-contiguous float4 stores.

#define BATCH     16384
#define IN_SIZE   448
#define OUT_SIZE  448
#define W_SIZE    14336
#define NELEM     64
#define RTILE     64
#define TMAX      8           // 512 rows/element >> max bucket (~310, 16 sigma)

typedef __attribute__((ext_vector_type(8))) short short8;
typedef __attribute__((ext_vector_type(8))) unsigned short us8;
typedef __attribute__((ext_vector_type(4))) float f32x4;

__device__ __forceinline__ unsigned short f2bf(float f) {
    unsigned int u = __float_as_uint(f);
    u += 0x7fffu + ((u >> 16) & 1u);        // round-to-nearest-even
    return (unsigned short)(u >> 16);
}

// ---------------- per-segment worker (scan inside, W loads first) ------------

template <int MI, int MO, int D, int XOFF, int YOFF, int SRC>
__device__ __forceinline__ void do_seg(const float* __restrict__ x,
                                       const float* __restrict__ we,
                                       const int* __restrict__ widx,
                                       int e, int lo,
                                       float* __restrict__ out,
                                       unsigned short* lds,
                                       int* rid_s, int* wsum, int t) {
    constexpr int XP   = MI * D + 8;         // x row stride (halves)
    constexpr int WSTR = MI + 8;             // W row stride (halves), %8==0
    constexpr int LP   = MO + 4;             // W temp [i][o] stride, %4==0
    constexpr int NT   = MO / 16;
    constexpr int KB   = MI / 32;
    constexpr int CNT  = MI * MO;
    constexpr int C8   = WSTR / 8;           // 16B chunks per W out row
    constexpr int NW   = (CNT + 2047) / 2048;// max float4 W-iters per thread
    constexpr int FPT  = (MI * D) / 8;       // floats per thread (8 thr/row)
    constexpr int NQ   = FPT / 4;
    constexpr int MOD  = MO * D;
    constexpr int NTW  = (4 * D * NT) / 8;   // C-tiles per wave (3/6/5)
    constexpr int F4R  = MOD / 4;

    unsigned short* lds_w = lds;             // [o][i] packed, MO*WSTR halves
    unsigned short* lw    = lds + MO * WSTR; // temp [i][o], MI*LP halves
    unsigned short* lds_x = lds + MO * WSTR; // x tile (after lw is consumed)

    // 0. W phase-A loads issue first — latency hides under the scan below
    float4 wv4[NW];
    #pragma unroll
    for (int q = 0; q < NW; ++q) {
        const int g = t * 4 + q * 2048;
        if (g < CNT) wv4[q] = *(const float4*)(we + SRC + g);
    }

    // 1. int4-vectorized rank-scan: bit (k*4+b) <-> row 4*(k*512+t)+b
    int nrows;
    {
        const int4* __restrict__ wp = (const int4*)widx;
        unsigned int m = 0;
        #pragma unroll
        for (int k = 0; k < 8; ++k) {
            const int4 v = wp[k * 512 + t];
            m |= (unsigned int)(v.x == e) << (k * 4 + 0);
            m |= (unsigned int)(v.y == e) << (k * 4 + 1);
            m |= (unsigned int)(v.z == e) << (k * 4 + 2);
            m |= (unsigned int)(v.w == e) << (k * 4 + 3);
        }
        const int c = __popc(m);
        int xacc = c;
        #pragma unroll
        for (int d = 1; d < 64; d <<= 1) {
            const int v = __shfl_up(xacc, d, 64);
            if ((t & 63) >= d) xacc += v;
        }
        if ((t & 63) == 63) wsum[t >> 6] = xacc;
        __syncthreads();
        int cnt = 0, wbase = 0;
        #pragma unroll
        for (int wv = 0; wv < 8; ++wv) {
            cnt += wsum[wv];                 // cnt stays in registers (uniform)
            wbase += (wv < (t >> 6)) ? wsum[wv] : 0;
        }
        if (lo >= cnt) return;               // uniform exit across the block
        nrows = min(RTILE, cnt - lo);
        const int p = wbase + xacc - c;      // exclusive prefix over 512 thr
        if (p < lo + RTILE && p + c > lo) {
            unsigned int mm = m;
            int k = p;
            while (mm) {
                const int beta = __ffs(mm) - 1;
                if (k >= lo)
                    rid_s[k - lo] = (beta >> 2) * 2048 + t * 4 + (beta & 3);
                ++k;
                if (k >= lo + RTILE) break;
                mm &= mm - 1;
            }
        }
    }

    // 2. W phase A writes: bf16 -> lw[i*LP + o]
    #pragma unroll
    for (int q = 0; q < NW; ++q) {
        const int g = t * 4 + q * 2048;
        if (g < CNT) {
            const int i = g / MO, o = g - i * MO;
            ushort4 w = { f2bf(wv4[q].x), f2bf(wv4[q].y),
                          f2bf(wv4[q].z), f2bf(wv4[q].w) };
            *(ushort4*)&lw[i * LP + o] = w;
        }
    }
    __syncthreads();                         // publishes lw AND rid_s

    // x gather clause issues now — overlaps the W transpose below
    const int r = t >> 3, j = t & 7;         // 8 threads per row, 64 rows
    const float4* __restrict__ src4 =
        (const float4*)(x + (size_t)rid_s[min(r, nrows - 1)] * IN_SIZE + XOFF + j * FPT);
    float vv[FPT];
    #pragma unroll
    for (int q = 0; q < NQ; ++q) {
        const float4 v = src4[q];
        vv[q * 4 + 0] = v.x; vv[q * 4 + 1] = v.y;
        vv[q * 4 + 2] = v.z; vv[q * 4 + 3] = v.w;
    }

    // W phase B: transpose lw[i][o] -> lds_w[o*WSTR + i] as packed us8
    for (int c = t; c < MO * C8; c += 512) {
        const int o = c / C8, i0 = (c - o * C8) * 8;
        us8 w;
        #pragma unroll
        for (int k = 0; k < 8; ++k)
            w[k] = (i0 + k < MI) ? lw[(i0 + k) * LP + o] : (unsigned short)0;
        *(us8*)&lds_w[o * WSTR + i0] = w;
    }
    __syncthreads();                         // lw reads done; lds_w ready

    // packed de-interleave x -> lds_x (overwrites lw region)
    if (D == 1) {
        #pragma unroll
        for (int q = 0; q < NQ; ++q) {
            ushort4 w = { f2bf(vv[q * 4 + 0]), f2bf(vv[q * 4 + 1]),
                          f2bf(vv[q * 4 + 2]), f2bf(vv[q * 4 + 3]) };
            *(ushort4*)&lds_x[r * XP + j * FPT + q * 4] = w;
        }
    } else if (D == 3) {
        #pragma unroll
        for (int m = 0; m < 3; ++m) {        // i = j*8 + b, src lc = 3b + m
            us8 w;
            #pragma unroll
            for (int bq = 0; bq < 8; ++bq) w[bq] = f2bf(vv[3 * bq + m]);
            *(us8*)&lds_x[r * XP + m * MI + j * 8] = w;
        }
    } else {                                 // D == 5: i = j*4 + b, lc = 5b + m
        #pragma unroll
        for (int m = 0; m < 5; ++m) {
            ushort4 w = { f2bf(vv[m]), f2bf(vv[5 + m]),
                          f2bf(vv[10 + m]), f2bf(vv[15 + m]) };
            *(ushort4*)&lds_x[r * XP + m * MI + j * 4] = w;
        }
    }
    __syncthreads();

    // compute: C-tiles (4 row-tiles x D x NT) round-robin over 8 waves
    const int lane = t & 63, w = t >> 6;
    const int row_l = lane & 15, kg = lane >> 4;
    f32x4 accs[NTW];
    #pragma unroll
    for (int q = 0; q < NTW; ++q) {
        const int ct = w + q * 8;
        const int mIdx = ct / NT, nt = ct - mIdx * NT;
        const int mt = mIdx & 3, mch = mIdx >> 2;
        f32x4 acc = {0.f, 0.f, 0.f, 0.f};
        #pragma unroll
        for (int kb = 0; kb < KB; ++kb) {
            const short8 a = *(const short8*)&lds_x[(mt * 16 + row_l) * XP + mch * MI + kb * 32 + kg * 8];
            const short8 b = *(const short8*)&lds_w[(nt * 16 + row_l) * WSTR + kb * 32 + kg * 8];
            acc = __builtin_amdgcn_mfma_f32_16x16x32_bf16(a, b, acc, 0, 0, 0);
        }
        accs[q] = acc;
    }
    __syncthreads();                         // all waves done reading lds_x/lds_w

    // 2-pass transpose epilogue: 32 rows per pass through LDS f32 image
    float* __restrict__ lout = (float*)lds;
    #pragma unroll
    for (int p = 0; p < 2; ++p) {
        #pragma unroll
        for (int q = 0; q < NTW; ++q) {
            const int ct = w + q * 8;
            const int mIdx = ct / NT, nt = ct - mIdx * NT;
            const int mt = mIdx & 3, mch = mIdx >> 2;
            if ((mt >> 1) == p) {
                const int o = nt * 16 + row_l;
                #pragma unroll
                for (int jj = 0; jj < 4; ++jj) {
                    const int lm = (mt & 1) * 16 + kg * 4 + jj;
                    lout[lm * MOD + o * D + mch] = accs[q][jj];
                }
            }
        }
        __syncthreads();
        for (int idx = t; idx < 32 * F4R; idx += 512) {
            const int rr = idx / F4R, c = idx - rr * F4R;
            const int grow = p * 32 + rr;
            if (grow < nrows) {
                float4 v = *(const float4*)&lout[rr * MOD + c * 4];
                *(float4*)&out[(size_t)rid_s[grow] * OUT_SIZE + YOFF + c * 4] = v;
            }
        }
        if (p == 0) __syncthreads();
    }
}

// ---------------- the single kernel ----------------

__global__ __launch_bounds__(512) void gemm_kernel(
    const float* __restrict__ x, const float* __restrict__ weights,
    const int* __restrict__ widx, float* __restrict__ out) {
    // LDS (halves): seg0 9984 + max(9600, 6656) = 19584 (39.2 KB) is the max.
    __shared__ __align__(16) unsigned short lds[19584];
    __shared__ int rid_s[RTILE];
    __shared__ int wsum[8];

    const int t    = threadIdx.x;
    const int seg  = blockIdx.x / (NELEM * TMAX);
    const int rem  = blockIdx.x - seg * (NELEM * TMAX);
    const int e    = rem / TMAX;
    const int tile = rem - e * TMAX;
    const int lo   = tile * RTILE;

    const float* __restrict__ we = weights + (size_t)e * W_SIZE;
    if (seg == 0)
        do_seg<96, 96, 1,   0,   0,     0>(x, we, widx, e, lo, out, lds, rid_s, wsum, t);
    else if (seg == 1)
        do_seg<64, 64, 3,  96,  96,  9216>(x, we, widx, e, lo, out, lds, rid_s, wsum, t);
    else
        do_seg<32, 32, 5, 288, 288, 13312>(x, we, widx, e, lo, out, lds, rid_s, wsum, t);
}

// ---------------- launcher ----------------

extern "C" void kernel_launch(void* const* d_in, const int* in_sizes, int n_in,
                              void* d_out, int out_size, void* d_ws, size_t ws_size,
                              hipStream_t stream) {
    const float* weights = (const float*)d_in[0];   // [64, 14336] f32
    const float* x       = (const float*)d_in[1];   // [16384, 448] f32
    const int*   widx    = (const int*)d_in[2];     // [16384] int32
    float*       out     = (float*)d_out;           // [16384, 448] f32

    gemm_kernel<<<3 * NELEM * TMAX, 512, 0, stream>>>(x, weights, widx, out);
}